// Round 2
// baseline (56025.287 us; speedup 1.0000x reference)
//
#include <hip/hip_runtime.h>
#include <cstdint>
#include <cstddef>

// ---------------------------------------------------------------------------
// 5-layer stacked LSTM (B=4096, T=256, H=50, D_in=1) + FC head, fp32.
//
// R2: register-resident weights. 1024 blocks x 128 threads, 4 rows/block.
// Thread tid<100 owns gates (tid, tid+100): full 100-wide weight rows live in
// VGPRs (~208 regs), loaded once per layer from global (L2-resident).
// Per step the LDS traffic is only: 104 broadcast ds_read_b128 of xh per wave
// + 2 b128 gate writes + small pointwise ops. No per-step weight reads.
// h,x live in s_xh[4][112]; gates bounce through s_g[200][4].
// Inter-layer sequences go through d_ws (ys[block][t][r*50+hu], 209,715,200 B).
// ---------------------------------------------------------------------------

#define HSZ   50
#define G4    200
#define TS    256
#define RPB   4              // rows per block
#define NB    (4096 / RPB)   // 1024 blocks
#define NT    128            // threads per block (2 waves)
#define XH    112            // padded xh row: [0..49]=x, [50..55]=0, [56..105]=h, [106..111]=0
#define HOFF  56

__device__ __forceinline__ float sigf(float x) {
  return __builtin_amdgcn_rcpf(1.0f + __expf(-x));
}
__device__ __forceinline__ float tanh_f(float x) {
  return fmaf(2.0f, __builtin_amdgcn_rcpf(1.0f + __expf(-2.0f * x)), -1.0f);
}

// load a 50-float weight row (8B-aligned) into 13 float4 regs (tail zero-padded)
__device__ __forceinline__ void load_row50(const float* __restrict__ p, float4 w[13]) {
  #pragma unroll
  for (int kk = 0; kk < 12; ++kk) {
    float2 e0 = *(const float2*)(p + kk * 4);
    float2 e1 = *(const float2*)(p + kk * 4 + 2);
    w[kk] = make_float4(e0.x, e0.y, e1.x, e1.y);
  }
  float2 tl = *(const float2*)(p + 48);
  w[12] = make_float4(tl.x, tl.y, 0.0f, 0.0f);
}

__global__ void __launch_bounds__(NT, 2)
lstm5_kernel(const float* __restrict__ x,
             const float* __restrict__ w_ih0, const float* __restrict__ w_hh0,
             const float* __restrict__ b0,
             const float* __restrict__ w_ih,  const float* __restrict__ w_hh,
             const float* __restrict__ b,
             const float* __restrict__ fc_w,  const float* __restrict__ fc_b,
             float* __restrict__ out, float* __restrict__ ys)
{
  __shared__ __align__(16) float s_xh[RPB * XH];   // 1792 B
  __shared__ __align__(16) float s_g[G4 * RPB];    // 3200 B

  const int tid  = threadIdx.x;
  const int blk  = blockIdx.x;
  const int row0 = blk * RPB;
  float* __restrict__ ysb = ys + (size_t)blk * (TS * G4);

  // register weight set for this thread's two gates (g0=tid, g1=tid+100)
  float4 wih0[13], wih1[13], whh0[13], whh1[13];
  float  bias0 = 0.0f, bias1 = 0.0f, wx0 = 0.0f, wx1 = 0.0f;

  for (int layer = 0; layer < 5; ++layer) {
    // ---------------- load this layer's weights into registers -------------
    if (tid < 100) {
      const int g0 = tid, g1 = tid + 100;
      if (layer == 0) {
        wx0 = w_ih0[g0];  wx1 = w_ih0[g1];
        load_row50(w_hh0 + (size_t)g0 * HSZ, whh0);
        load_row50(w_hh0 + (size_t)g1 * HSZ, whh1);
        bias0 = b0[g0];  bias1 = b0[g1];
      } else {
        const float* Wih = w_ih + (size_t)(layer - 1) * G4 * HSZ;
        const float* Whh = w_hh + (size_t)(layer - 1) * G4 * HSZ;
        const float* Bl  = b    + (size_t)(layer - 1) * G4;
        load_row50(Wih + (size_t)g0 * HSZ, wih0);
        load_row50(Wih + (size_t)g1 * HSZ, wih1);
        load_row50(Whh + (size_t)g0 * HSZ, whh0);
        load_row50(Whh + (size_t)g1 * HSZ, whh1);
        bias0 = Bl[g0];  bias1 = Bl[g1];
      }
    }

    // ---------------- init state: zero xh, fill x_0 ------------------------
    for (int i = tid; i < RPB * XH; i += NT) s_xh[i] = 0.0f;
    __syncthreads();
    if (layer == 0) {
      if (tid < RPB) s_xh[tid * XH] = x[(size_t)(row0 + tid) * TS];
    } else if (tid < 100) {
      const int r0_ = (tid >= 50);
      const int hu_ = tid - r0_ * 50;
      s_xh[r0_ * XH + hu_]       = ysb[tid];
      s_xh[(2 + r0_) * XH + hu_] = ysb[100 + tid];
    }
    float cst0 = 0.0f, cst1 = 0.0f;   // cell state for this thread's 2 pointwise items
    __syncthreads();

    // ---------------------------- time loop --------------------------------
    for (int t = 0; t < TS; ++t) {
      // phase 1: prefetch x_{t+1} into registers (hidden under GEMM)
      const int nt = (t + 1 < TS) ? (t + 1) : t;
      float pf0 = 0.0f, pf1 = 0.0f;
      if (layer == 0) {
        if (tid < RPB) pf0 = x[(size_t)(row0 + tid) * TS + nt];
      } else if (tid < 100) {
        pf0 = ysb[nt * G4 + tid];
        pf1 = ysb[nt * G4 + 100 + tid];
      }

      // phase 2: gate GEMM from register weights + broadcast LDS reads
      if (tid < 100) {
        float a0[RPB], a1[RPB];
        #pragma unroll
        for (int r = 0; r < RPB; ++r) { a0[r] = bias0; a1[r] = bias1; }

        #pragma unroll
        for (int r = 0; r < RPB; ++r) {
          const float* base = s_xh + r * XH;
          if (layer == 0) {
            float xv = base[0];
            a0[r] = fmaf(wx0, xv, a0[r]);
            a1[r] = fmaf(wx1, xv, a1[r]);
          } else {
            #pragma unroll
            for (int kk = 0; kk < 13; ++kk) {
              float4 xv = *(const float4*)(base + kk * 4);
              a0[r] = fmaf(wih0[kk].x, xv.x, a0[r]);
              a0[r] = fmaf(wih0[kk].y, xv.y, a0[r]);
              a0[r] = fmaf(wih0[kk].z, xv.z, a0[r]);
              a0[r] = fmaf(wih0[kk].w, xv.w, a0[r]);
              a1[r] = fmaf(wih1[kk].x, xv.x, a1[r]);
              a1[r] = fmaf(wih1[kk].y, xv.y, a1[r]);
              a1[r] = fmaf(wih1[kk].z, xv.z, a1[r]);
              a1[r] = fmaf(wih1[kk].w, xv.w, a1[r]);
            }
          }
          #pragma unroll
          for (int kk = 0; kk < 13; ++kk) {
            float4 xv = *(const float4*)(base + HOFF + kk * 4);
            a0[r] = fmaf(whh0[kk].x, xv.x, a0[r]);
            a0[r] = fmaf(whh0[kk].y, xv.y, a0[r]);
            a0[r] = fmaf(whh0[kk].z, xv.z, a0[r]);
            a0[r] = fmaf(whh0[kk].w, xv.w, a0[r]);
            a1[r] = fmaf(whh1[kk].x, xv.x, a1[r]);
            a1[r] = fmaf(whh1[kk].y, xv.y, a1[r]);
            a1[r] = fmaf(whh1[kk].z, xv.z, a1[r]);
            a1[r] = fmaf(whh1[kk].w, xv.w, a1[r]);
          }
        }
        *(float4*)&s_g[tid * 4]         = make_float4(a0[0], a0[1], a0[2], a0[3]);
        *(float4*)&s_g[(tid + 100) * 4] = make_float4(a1[0], a1[1], a1[2], a1[3]);
      }
      __syncthreads();   // gates visible; all xh reads of step t done

      // phase 3: stash prefetched x_{t+1}
      if (layer == 0) {
        if (tid < RPB) s_xh[tid * XH] = pf0;
      } else if (tid < 100) {
        const int r0_ = (tid >= 50);
        const int hu_ = tid - r0_ * 50;
        s_xh[r0_ * XH + hu_]       = pf0;
        s_xh[(2 + r0_) * XH + hu_] = pf1;
      }

      // phase 4: pointwise cell update (thread tid<100: hu=tid>>1, rows r0,r0+1)
      if (tid < 100) {
        const int hu = tid >> 1;
        const int r0_ = (tid & 1) * 2;
        float2 gi = *(const float2*)&s_g[(hu      ) * 4 + r0_];
        float2 gf = *(const float2*)&s_g[(hu +  50) * 4 + r0_];
        float2 gg = *(const float2*)&s_g[(hu + 100) * 4 + r0_];
        float2 go = *(const float2*)&s_g[(hu + 150) * 4 + r0_];

        float c0 = fmaf(sigf(gf.x), cst0, sigf(gi.x) * tanh_f(gg.x));
        float h0 = sigf(go.x) * tanh_f(c0);
        cst0 = c0;
        float c1 = fmaf(sigf(gf.y), cst1, sigf(gi.y) * tanh_f(gg.y));
        float h1 = sigf(go.y) * tanh_f(c1);
        cst1 = c1;

        s_xh[(r0_    ) * XH + HOFF + hu] = h0;
        s_xh[(r0_ + 1) * XH + HOFF + hu] = h1;
        if (layer < 4) {
          ysb[t * G4 + (r0_    ) * HSZ + hu] = h0;
          ysb[t * G4 + (r0_ + 1) * HSZ + hu] = h1;
        }
      }
      __syncthreads();   // h_t and x_{t+1} visible for next step
    }
  }

  // ------------------------------ FC head ---------------------------------
  if (tid < RPB) {
    float a = fc_b[0];
    const float* hr = s_xh + tid * XH + HOFF;
    #pragma unroll
    for (int k = 0; k < HSZ; ++k) a = fmaf(hr[k], fc_w[k], a);
    out[row0 + tid] = a;
  }
}

extern "C" void kernel_launch(void* const* d_in, const int* in_sizes, int n_in,
                              void* d_out, int out_size, void* d_ws, size_t ws_size,
                              hipStream_t stream) {
  (void)in_sizes; (void)n_in; (void)out_size; (void)ws_size;
  const float* x     = (const float*)d_in[0];
  const float* w_ih0 = (const float*)d_in[1];
  const float* w_hh0 = (const float*)d_in[2];
  const float* b0    = (const float*)d_in[3];
  const float* w_ih  = (const float*)d_in[4];
  const float* w_hh  = (const float*)d_in[5];
  const float* b     = (const float*)d_in[6];
  const float* fc_w  = (const float*)d_in[7];
  const float* fc_b  = (const float*)d_in[8];
  float* out = (float*)d_out;
  float* ys  = (float*)d_ws;   // 1024 blocks * 256 t * 200 * 4 B = 209,715,200 B

  hipLaunchKernelGGL(lstm5_kernel, dim3(NB), dim3(NT), 0, stream,
                     x, w_ih0, w_hh0, b0, w_ih, w_hh, b, fc_w, fc_b, out, ys);
}

// Round 8
// 10735.255 us; speedup vs baseline: 5.2188x; 5.2188x over previous
//
#include <hip/hip_runtime.h>
#include <cstdint>
#include <cstddef>

// ---------------------------------------------------------------------------
// 5-layer stacked LSTM (B=4096, T=256, H=50, D_in=1) + FC head, fp32.
//
// Resubmit #5 (R3-R7 benches all GPUAcquisitionTimeout — never ran).
// Register-resident weights, 1 gate/thread (R2 spilled at 2 gates/thread:
// 208 weight VGPRs + overhead > cap -> 126 GB of scratch HBM traffic).
// 1024 blocks x 256 threads, 4 batch rows/block. Thread tid<200 owns gate
// g=tid: its 100 weights live in 26 float4 = 104 VGPRs, loaded once per layer
// from global (L2-resident). Per step: 104 broadcast ds_read_b128 of xh per
// wave + 1 b128 gate write + lane-consecutive pointwise ops.
// Pointwise/ysb mapping: item tid = (hu = tid>>2, row = tid&3) -> all LDS and
// global accesses lane-consecutive (conflict-free / coalesced).
// Inter-layer sequences via d_ws: ysb[block][t][hu*4+row], 209,715,200 B.
// ---------------------------------------------------------------------------

#define HSZ   50
#define G4    200
#define TS    256
#define RPB   4              // batch rows per block
#define NB    (4096 / RPB)   // 1024 blocks
#define NT    256            // threads (4 waves)
#define XH    112            // xh row: [0..49]=x, [50..55]=pad0, [56..105]=h, [106..111]=pad0
#define HOFF  56

__device__ __forceinline__ float sigf(float x) {
  return __builtin_amdgcn_rcpf(1.0f + __expf(-x));
}
__device__ __forceinline__ float tanh_f(float x) {
  return fmaf(2.0f, __builtin_amdgcn_rcpf(1.0f + __expf(-2.0f * x)), -1.0f);
}

// load a 50-float weight row (8B-aligned) into 13 float4 regs, tail zeroed
__device__ __forceinline__ void load_row50(const float* __restrict__ p, float4 w[13]) {
  #pragma unroll
  for (int kk = 0; kk < 12; ++kk) {
    float2 e0 = *(const float2*)(p + kk * 4);
    float2 e1 = *(const float2*)(p + kk * 4 + 2);
    w[kk] = make_float4(e0.x, e0.y, e1.x, e1.y);
  }
  float2 tl = *(const float2*)(p + 48);
  w[12] = make_float4(tl.x, tl.y, 0.0f, 0.0f);
}

__global__ void __launch_bounds__(NT, 2)
lstm5_kernel(const float* __restrict__ x,
             const float* __restrict__ w_ih0, const float* __restrict__ w_hh0,
             const float* __restrict__ b0,
             const float* __restrict__ w_ih,  const float* __restrict__ w_hh,
             const float* __restrict__ b,
             const float* __restrict__ fc_w,  const float* __restrict__ fc_b,
             float* __restrict__ out, float* __restrict__ ys)
{
  __shared__ __align__(16) float s_xh[RPB * XH];   // 1792 B
  __shared__ __align__(16) float s_g[G4 * RPB];    // 3200 B, [gate][row]

  const int tid  = threadIdx.x;
  const int blk  = blockIdx.x;
  const int row0 = blk * RPB;
  const bool gt  = (tid < G4);
  const int  g   = gt ? tid : (G4 - 1);  // clamped: lanes 200-255 duplicate gate 199, never write
  const int  pr  = tid & 3;              // pointwise row
  const int  phu = tid >> 2;             // pointwise hidden unit
  float* __restrict__ ysb = ys + (size_t)blk * (TS * G4);

  float4 wih[13], whh[13];
  float  bias = 0.0f, wx0 = 0.0f;

  for (int layer = 0; layer < 5; ++layer) {
    // -------------- load this thread's gate weights into registers ----------
    if (layer == 0) {
      wx0  = w_ih0[g];
      load_row50(w_hh0 + (size_t)g * HSZ, whh);
      bias = b0[g];
    } else {
      const float* Wih = w_ih + (size_t)(layer - 1) * G4 * HSZ;
      const float* Whh = w_hh + (size_t)(layer - 1) * G4 * HSZ;
      load_row50(Wih + (size_t)g * HSZ, wih);
      load_row50(Whh + (size_t)g * HSZ, whh);
      bias = b[(size_t)(layer - 1) * G4 + g];
    }

    // -------------------- init state: zero xh, fill x_0 ---------------------
    for (int i = tid; i < RPB * XH; i += NT) s_xh[i] = 0.0f;
    __syncthreads();
    if (layer == 0) {
      if (tid < RPB) s_xh[tid * XH] = x[(size_t)(row0 + tid) * TS];
    } else if (gt) {
      s_xh[pr * XH + phu] = ysb[tid];     // ysb[t=0][hu*4+r]
    }
    float cst = 0.0f;                     // cell state for item (pr, phu)
    __syncthreads();

    // ------------------------------ time loop -------------------------------
    for (int t = 0; t < TS; ++t) {
      // prefetch x_{t+1} (latency hidden under the gate GEMM)
      const int nt2 = (t + 1 < TS) ? (t + 1) : t;
      float pf = 0.0f;
      if (layer == 0) {
        if (tid < RPB) pf = x[(size_t)(row0 + tid) * TS + nt2];
      } else if (gt) {
        pf = ysb[nt2 * G4 + tid];
      }

      // gate GEMM: a[r] = bias + W_ih[g,:]*x_r + W_hh[g,:]*h_r
      float a[RPB];
      #pragma unroll
      for (int r = 0; r < RPB; ++r) a[r] = bias;

      #pragma unroll
      for (int r = 0; r < RPB; ++r) {
        const float* bx = s_xh + r * XH;
        if (layer == 0) {
          a[r] = fmaf(wx0, bx[0], a[r]);
        } else {
          #pragma unroll
          for (int kk = 0; kk < 13; ++kk) {
            float4 xv = *(const float4*)(bx + kk * 4);   // broadcast b128
            a[r] = fmaf(wih[kk].x, xv.x, a[r]);
            a[r] = fmaf(wih[kk].y, xv.y, a[r]);
            a[r] = fmaf(wih[kk].z, xv.z, a[r]);
            a[r] = fmaf(wih[kk].w, xv.w, a[r]);
          }
        }
        #pragma unroll
        for (int kk = 0; kk < 13; ++kk) {
          float4 hv = *(const float4*)(bx + HOFF + kk * 4);
          a[r] = fmaf(whh[kk].x, hv.x, a[r]);
          a[r] = fmaf(whh[kk].y, hv.y, a[r]);
          a[r] = fmaf(whh[kk].z, hv.z, a[r]);
          a[r] = fmaf(whh[kk].w, hv.w, a[r]);
        }
      }
      if (gt) *(float4*)&s_g[g * 4] = make_float4(a[0], a[1], a[2], a[3]);
      __syncthreads();   // gates visible; xh reads of step t complete

      // stash prefetched x_{t+1} into the x region
      if (layer == 0) {
        if (tid < RPB) s_xh[tid * XH] = pf;
      } else if (gt) {
        s_xh[pr * XH + phu] = pf;
      }

      // pointwise cell update: item (pr, phu); all reads lane-consecutive b32
      if (gt) {
        float gi = s_g[ phu        * 4 + pr];
        float gf = s_g[(phu +  50) * 4 + pr];
        float gg = s_g[(phu + 100) * 4 + pr];
        float go = s_g[(phu + 150) * 4 + pr];
        float c  = fmaf(sigf(gf), cst, sigf(gi) * tanh_f(gg));
        cst = c;
        float h  = sigf(go) * tanh_f(c);
        s_xh[pr * XH + HOFF + phu] = h;
        if (layer < 4) ysb[t * G4 + tid] = h;   // coalesced b32
      }
      __syncthreads();   // h_t and x_{t+1} visible for next step
    }
  }

  // ------------------------------- FC head ---------------------------------
  if (tid < RPB) {
    float a2 = fc_b[0];
    const float* hr = s_xh + tid * XH + HOFF;
    #pragma unroll
    for (int k = 0; k < HSZ; ++k) a2 = fmaf(hr[k], fc_w[k], a2);
    out[row0 + tid] = a2;
  }
}

extern "C" void kernel_launch(void* const* d_in, const int* in_sizes, int n_in,
                              void* d_out, int out_size, void* d_ws, size_t ws_size,
                              hipStream_t stream) {
  (void)in_sizes; (void)n_in; (void)out_size; (void)ws_size;
  const float* x     = (const float*)d_in[0];
  const float* w_ih0 = (const float*)d_in[1];
  const float* w_hh0 = (const float*)d_in[2];
  const float* b0    = (const float*)d_in[3];
  const float* w_ih  = (const float*)d_in[4];
  const float* w_hh  = (const float*)d_in[5];
  const float* b     = (const float*)d_in[6];
  const float* fc_w  = (const float*)d_in[7];
  const float* fc_b  = (const float*)d_in[8];
  float* out = (float*)d_out;
  float* ys  = (float*)d_ws;   // 1024 * 256 * 200 * 4 B = 209,715,200 B

  hipLaunchKernelGGL(lstm5_kernel, dim3(NB), dim3(NT), 0, stream,
                     x, w_ih0, w_hh0, b0, w_ih, w_hh, b, fc_w, fc_b, out, ys);
}